// Round 8
// baseline (862.721 us; speedup 1.0000x reference)
//
#include <hip/hip_runtime.h>
#include <hip/hip_bf16.h>
#include <math.h>

// ---------------------------------------------------------------------------
// AdvancedTransactionGNN: 3-layer GAT on MI355X.
// Layers 1-2 GEMM: bf16 MFMA (16x16x32), 128x128x64 tiles, 4 waves.
// Layer 3 GEMM: fp32 vector (tiny; keeps final map accurate).
// Aggregation: per-(node,head) softmax stats (m, 1/s) precomputed by a
// wave-per-node norm kernel; agg stage phase computes normalized p once per
// (edge,head); inner loop is pure gather+FMA (no exp/max/rescale).
// ---------------------------------------------------------------------------

typedef __attribute__((ext_vector_type(8))) short bf16x8;   // 8 bf16 = 4 VGPR
typedef __attribute__((ext_vector_type(4))) float f32x4;
typedef __attribute__((ext_vector_type(2))) unsigned int u32x2;

// ---------------- storage conversion helpers ----------------

__device__ inline float bf2f(unsigned short u) {
    return __uint_as_float(((unsigned int)u) << 16);
}
__device__ inline unsigned short f2bf(float f) {   // round-nearest-even
    unsigned int x = __float_as_uint(f);
    return (unsigned short)((x + 0x7FFFu + ((x >> 16) & 1u)) >> 16);
}
__device__ inline unsigned int pack2bf(float lo, float hi) {
    return (unsigned int)f2bf(lo) | ((unsigned int)f2bf(hi) << 16);
}

template <typename T> __device__ inline float  ldf(const T* p);
template <> __device__ inline float ldf<float>(const float* p) { return *p; }
template <> __device__ inline float ldf<unsigned short>(const unsigned short* p) { return bf2f(*p); }

template <typename T> __device__ inline float4 ld4f(const T* p);
template <> __device__ inline float4 ld4f<float>(const float* p) { return *(const float4*)p; }
template <> __device__ inline float4 ld4f<unsigned short>(const unsigned short* p) {
    short4 v = *(const short4*)p;
    return make_float4(bf2f((unsigned short)v.x), bf2f((unsigned short)v.y),
                       bf2f((unsigned short)v.z), bf2f((unsigned short)v.w));
}

template <typename T> __device__ inline float2 ld2f(const T* p);
template <> __device__ inline float2 ld2f<float>(const float* p) { return *(const float2*)p; }
template <> __device__ inline float2 ld2f<unsigned short>(const unsigned short* p) {
    short2 v = *(const short2*)p;
    return make_float2(bf2f((unsigned short)v.x), bf2f((unsigned short)v.y));
}

template <typename T> __device__ inline void stf(T* p, float v);
template <> __device__ inline void stf<float>(float* p, float v) { *p = v; }
template <> __device__ inline void stf<unsigned short>(unsigned short* p, float v) { *p = f2bf(v); }

// ---------------- prep: fp32 -> bf16 convert / weight transpose -------------

__global__ void cvt_bf_kernel(const float* __restrict__ in, unsigned short* __restrict__ out, int n4) {
    int i = blockIdx.x * blockDim.x + threadIdx.x;
    if (i < n4) {
        float4 v = ((const float4*)in)[i];
        short4 s;
        s.x = (short)f2bf(v.x); s.y = (short)f2bf(v.y);
        s.z = (short)f2bf(v.z); s.w = (short)f2bf(v.w);
        ((short4*)out)[i] = s;
    }
}

// Wt[n][k] = bf16(W[k][n]); K, NOUT multiples of 16.
__global__ void transpose_bf_kernel(const float* __restrict__ W, unsigned short* __restrict__ Wt,
                                    int K, int NOUT) {
    __shared__ float tile[16][17];
    int kb = blockIdx.y * 16, nb = blockIdx.x * 16;
    int tx = threadIdx.x, ty = threadIdx.y;
    tile[ty][tx] = W[(size_t)(kb + ty) * NOUT + nb + tx];
    __syncthreads();
    Wt[(size_t)(nb + ty) * K + kb + tx] = f2bf(tile[tx][ty]);
}

// ---------------- CSR build ----------------

__global__ void count_kernel(const int* __restrict__ ei, int* __restrict__ deg, int E, int N) {
    int i = blockIdx.x * blockDim.x + threadIdx.x;
    if (i < E) {
        int dst = ei[E + i];
        if ((unsigned)dst < (unsigned)N) atomicAdd(&deg[dst], 1);
    }
}

__global__ __launch_bounds__(1024) void scan_kernel(const int* __restrict__ deg,
                                                    int* __restrict__ offs,
                                                    int* __restrict__ cursor, int n) {
    __shared__ int sdata[1024];
    __shared__ int carry_s;
    int tid = threadIdx.x;
    if (tid == 0) carry_s = 0;
    __syncthreads();
    for (int base = 0; base < n; base += 1024) {
        int i = base + tid;
        int v = (i < n) ? (deg[i] + 1) : 0;   // +1: self-loop
        sdata[tid] = v;
        __syncthreads();
        #pragma unroll
        for (int off = 1; off < 1024; off <<= 1) {
            int t = (tid >= off) ? sdata[tid - off] : 0;
            __syncthreads();
            sdata[tid] += t;
            __syncthreads();
        }
        int incl = sdata[tid] + carry_s;
        if (i < n) {
            offs[i + 1] = incl;
            cursor[i] = incl - v;
        }
        __syncthreads();
        if (tid == 1023) carry_s = incl;
        __syncthreads();
    }
    if (tid == 0) offs[0] = 0;
}

__global__ void fill_kernel(const int* __restrict__ ei, int* __restrict__ cursor,
                            int* __restrict__ col, int E, int N) {
    int i = blockIdx.x * blockDim.x + threadIdx.x;
    int cap = E + N;
    if (i < E) {
        int src = ei[i];
        int dst = ei[E + i];
        if ((unsigned)src < (unsigned)N && (unsigned)dst < (unsigned)N) {
            int pos = atomicAdd(&cursor[dst], 1);
            if ((unsigned)pos < (unsigned)cap) col[pos] = src;
        }
    } else if (i < cap) {
        int n = i - E;
        int pos = atomicAdd(&cursor[n], 1);
        if ((unsigned)pos < (unsigned)cap) col[pos] = n;
    }
}

// ---------------- bf16 MFMA GEMM: C[M,NOUT] = A[M,K_] @ Bt[NOUT,K_]^T --------

template <int K_, int NOUT, typename TC>
__global__ __launch_bounds__(256) void gemm_mfma(const unsigned short* __restrict__ A,
                                                 const unsigned short* __restrict__ Bt,
                                                 TC* __restrict__ C, int M) {
    constexpr int BM = 128, BN = 128, BK = 64;
    constexpr int LDT = BK + 8;
    __shared__ unsigned short Als[BM][LDT];
    __shared__ unsigned short Bls[BN][LDT];

    int tid = threadIdx.x;
    int lane = tid & 63, wave = tid >> 6;
    int wr = (wave >> 1) * 64, wc = (wave & 1) * 64;
    int row0 = blockIdx.x * BM, col0 = blockIdx.y * BN;

    int sr = tid >> 3;
    int sk = (tid & 7) * 8;

    f32x4 acc[4][4] = {};

    for (int k0 = 0; k0 < K_; k0 += BK) {
        #pragma unroll
        for (int i = 0; i < 4; ++i) {
            int r = sr + i * 32;
            int gr = row0 + r;
            uint4 va = make_uint4(0u, 0u, 0u, 0u);
            if (gr < M) va = *(const uint4*)(A + (size_t)gr * K_ + k0 + sk);
            *(uint4*)&Als[r][sk] = va;
            uint4 vb = *(const uint4*)(Bt + (size_t)(col0 + r) * K_ + k0 + sk);
            *(uint4*)&Bls[r][sk] = vb;
        }
        __syncthreads();
        #pragma unroll
        for (int kh = 0; kh < 2; ++kh) {
            int kk = kh * 32 + (lane >> 4) * 8;
            bf16x8 a[4], b[4];
            #pragma unroll
            for (int m = 0; m < 4; ++m)
                a[m] = *(const bf16x8*)&Als[wr + m * 16 + (lane & 15)][kk];
            #pragma unroll
            for (int n = 0; n < 4; ++n)
                b[n] = *(const bf16x8*)&Bls[wc + n * 16 + (lane & 15)][kk];
            #pragma unroll
            for (int m = 0; m < 4; ++m)
                #pragma unroll
                for (int n = 0; n < 4; ++n)
                    acc[m][n] = __builtin_amdgcn_mfma_f32_16x16x32_bf16(a[m], b[n], acc[m][n], 0, 0, 0);
        }
        __syncthreads();
    }

    int fr = lane & 15, fq = lane >> 4;
    #pragma unroll
    for (int m = 0; m < 4; ++m) {
        #pragma unroll
        for (int j = 0; j < 4; ++j) {
            int r = row0 + wr + m * 16 + fq * 4 + j;
            if (r < M) {
                #pragma unroll
                for (int n = 0; n < 4; ++n)
                    stf(C + (size_t)r * NOUT + col0 + wc + n * 16 + fr, acc[m][n][j]);
            }
        }
    }
}

// ---------------- fp32 GEMM (layer 3): C = A @ B ----------------

template <int K_, int NOUT, typename TA, typename TC>
__global__ __launch_bounds__(256) void gemm_kernel(const TA* __restrict__ A,
                                                   const float* __restrict__ B,
                                                   TC* __restrict__ C, int M) {
    constexpr int BM = 128, BN = 64, BK = 16;
    __shared__ float As[BK][BM + 4];
    __shared__ float Bs[BK][BN];

    int tid = threadIdx.x;
    int tx = tid % 16;
    int ty = tid / 16;
    int row0 = blockIdx.x * BM;
    int col0 = blockIdx.y * BN;

    int ar0 = tid / 4;
    int ak  = (tid % 4) * 4;
    int bk  = tid / 16;
    int bn  = (tid % 16) * 4;

    float acc[8][4];
    #pragma unroll
    for (int i = 0; i < 8; ++i)
        #pragma unroll
        for (int j = 0; j < 4; ++j) acc[i][j] = 0.f;

    for (int k0 = 0; k0 < K_; k0 += BK) {
        #pragma unroll
        for (int i = 0; i < 2; ++i) {
            int r = row0 + ar0 + i * 64;
            float4 v = make_float4(0.f, 0.f, 0.f, 0.f);
            if (r < M) v = ld4f(A + (size_t)r * K_ + k0 + ak);
            As[ak + 0][ar0 + i * 64] = v.x;
            As[ak + 1][ar0 + i * 64] = v.y;
            As[ak + 2][ar0 + i * 64] = v.z;
            As[ak + 3][ar0 + i * 64] = v.w;
        }
        float4 w = *(const float4*)(B + (size_t)(k0 + bk) * NOUT + col0 + bn);
        *(float4*)&Bs[bk][bn] = w;
        __syncthreads();

        #pragma unroll
        for (int k = 0; k < BK; ++k) {
            float4 a0 = *(const float4*)&As[k][ty * 8];
            float4 a1 = *(const float4*)&As[k][ty * 8 + 4];
            float4 b0 = *(const float4*)&Bs[k][tx * 4];
            float a[8] = {a0.x, a0.y, a0.z, a0.w, a1.x, a1.y, a1.z, a1.w};
            float b[4] = {b0.x, b0.y, b0.z, b0.w};
            #pragma unroll
            for (int i = 0; i < 8; ++i)
                #pragma unroll
                for (int j = 0; j < 4; ++j) acc[i][j] = fmaf(a[i], b[j], acc[i][j]);
        }
        __syncthreads();
    }

    #pragma unroll
    for (int i = 0; i < 8; ++i) {
        int r = row0 + ty * 8 + i;
        if (r < M) {
            #pragma unroll
            for (int j = 0; j < 4; ++j)
                stf(C + (size_t)r * NOUT + col0 + tx * 4 + j, acc[i][j]);
        }
    }
}

// ---------------- alpha dots ----------------

template <int H>
__global__ __launch_bounds__(256) void alpha128_kernel(const unsigned short* __restrict__ h,
                                                       const float* __restrict__ a_src,
                                                       const float* __restrict__ a_dst,
                                                       float* __restrict__ asb,
                                                       float* __restrict__ adb, int N) {
    int node = blockIdx.x * 4 + (threadIdx.x >> 6);
    if (node >= N) return;
    int lane = threadIdx.x & 63;
    const unsigned short* row = h + (size_t)node * (H * 128);
    #pragma unroll
    for (int it = 0; it < H / 4; ++it) {
        int head = it * 4 + (lane >> 4);
        int eoff = it * 512 + (lane >> 4) * 128 + (lane & 15) * 8;
        const unsigned short* p = row + eoff;
        float4 v0 = ld4f(p);
        float4 v1 = ld4f(p + 4);
        const float* asp = a_src + head * 128 + (lane & 15) * 8;
        const float* adp = a_dst + head * 128 + (lane & 15) * 8;
        float4 s0 = *(const float4*)asp, s1 = *(const float4*)(asp + 4);
        float4 d0 = *(const float4*)adp, d1 = *(const float4*)(adp + 4);
        float r1 = v0.x * s0.x + v0.y * s0.y + v0.z * s0.z + v0.w * s0.w
                 + v1.x * s1.x + v1.y * s1.y + v1.z * s1.z + v1.w * s1.w;
        float r2 = v0.x * d0.x + v0.y * d0.y + v0.z * d0.z + v0.w * d0.w
                 + v1.x * d1.x + v1.y * d1.y + v1.z * d1.z + v1.w * d1.w;
        #pragma unroll
        for (int off = 1; off < 16; off <<= 1) {
            r1 += __shfl_xor(r1, off);
            r2 += __shfl_xor(r2, off);
        }
        if ((lane & 15) == 0) {
            asb[node * H + head] = r1;
            adb[node * H + head] = r2;
        }
    }
}

// generic (layer 3: H=1, D=64)
template <int H, int D, typename T>
__global__ __launch_bounds__(256) void alpha_kernel(const T* __restrict__ h,
                                                    const float* __restrict__ a_src,
                                                    const float* __restrict__ a_dst,
                                                    float* __restrict__ as_,
                                                    float* __restrict__ ad_, int N) {
    int wid = blockIdx.x * 4 + threadIdx.x / 64;
    int lane = threadIdx.x % 64;
    if (wid >= N * H) return;
    int n = wid / H, hh = wid % H;
    const T* hrow = h + (size_t)n * (H * D) + hh * D;
    float s1 = 0.f, s2 = 0.f;
    #pragma unroll
    for (int d = lane; d < D; d += 64) {
        float v = ldf(hrow + d);
        s1 = fmaf(v, a_src[hh * D + d], s1);
        s2 = fmaf(v, a_dst[hh * D + d], s2);
    }
    #pragma unroll
    for (int off = 32; off > 0; off >>= 1) {
        s1 += __shfl_down(s1, off);
        s2 += __shfl_down(s2, off);
    }
    if (lane == 0) {
        as_[n * H + hh] = s1;
        ad_[n * H + hh] = s2;
    }
}

// ---------------- softmax stats: per (node, head) m and 1/s ------------------
// One wave per node; lane -> (edge slot, head) with head = lane % H fixed.
// Reads only col + the small asb/adb tables (L2-resident).

template <int H>
__global__ __launch_bounds__(256) void norm_kernel(const float* __restrict__ asb,
                                                   const float* __restrict__ adb,
                                                   const int* __restrict__ offs,
                                                   const int* __restrict__ col,
                                                   float* __restrict__ mArr,
                                                   float* __restrict__ invArr, int N) {
    int node = blockIdx.x * 4 + (threadIdx.x >> 6);
    if (node >= N) return;
    int lane = threadIdx.x & 63;
    int start = offs[node];
    int nval = (offs[node + 1] - start) * H;
    int h = lane % H;                    // 64 % H == 0 -> constant per lane
    float adn = adb[node * H + h];

    float m = -1e30f;
    for (int i = lane; i < nval; i += 64) {
        int s = col[start + i / H];
        float e = asb[s * H + h] + adn;
        e = (e > 0.f) ? e : 0.2f * e;
        m = fmaxf(m, e);
    }
    #pragma unroll
    for (int off = H; off < 64; off <<= 1) m = fmaxf(m, __shfl_xor(m, off));

    float ss = 0.f;
    for (int i = lane; i < nval; i += 64) {
        int s = col[start + i / H];
        float e = asb[s * H + h] + adn;
        e = (e > 0.f) ? e : 0.2f * e;
        ss += __expf(e - m);
    }
    #pragma unroll
    for (int off = H; off < 64; off <<= 1) ss += __shfl_xor(ss, off);

    if (lane < H) {
        mArr[node * H + h] = m;
        invArr[node * H + h] = 1.f / (ss + 1e-16f);
    }
}

// ---------------- GAT aggregation: precomputed softmax stats ----------------
// Stage phase computes normalized p once per (edge,head); inner loop is pure
// {LDS p read + h-row gather + cvt + FMA}, 4-way unrolled for MLP.

template <int H, int D, int BLOCK, bool DO_ELU, typename TIN, typename TOUT>
__global__ __launch_bounds__(BLOCK) void agg_kernel(const TIN* __restrict__ h,
                                                    const float* __restrict__ asb,
                                                    const float* __restrict__ adb,
                                                    const float* __restrict__ mArr,
                                                    const float* __restrict__ invArr,
                                                    const int* __restrict__ offs,
                                                    const int* __restrict__ col,
                                                    const float* __restrict__ bias,
                                                    TOUT* __restrict__ out, int N) {
    constexpr int C = H * D;
    constexpr int V = C / BLOCK;        // 4 (L1), 2 (L2), 1 (L3)
    constexpr int CH = BLOCK / H;       // 32, 64, 64
    __shared__ float p_s[CH * H];
    __shared__ int   col_s[CH];

    int node = blockIdx.x;
    int t = threadIdx.x;
    int c0 = t * V;
    int hh = c0 / D;
    int start = offs[node], end = offs[node + 1];

    int sj = t / H;                     // stage role: edge slot
    int sh = t % H;                     // stage role: head
    float adn_st = adb[node * H + sh];
    float m_st   = mArr[node * H + sh];
    float inv_st = invArr[node * H + sh];

    float acc[V];
    #pragma unroll
    for (int v = 0; v < V; ++v) acc[v] = 0.f;

    for (int base = start; base < end; base += CH) {
        int len = min(CH, end - base);
        __syncthreads();                // previous chunk's LDS readers done
        if (t < len * H) {              // sj < len
            int s = col[base + sj];
            if ((unsigned)s >= (unsigned)N) s = node;
            float e = asb[s * H + sh] + adn_st;
            e = (e > 0.f) ? e : 0.2f * e;
            p_s[t] = __expf(e - m_st) * inv_st;
            if (sh == 0) col_s[sj] = s;
        }
        __syncthreads();

        int j = 0;
        for (; j + 3 < len; j += 4) {
            int s0 = col_s[j], s1 = col_s[j + 1], s2 = col_s[j + 2], s3 = col_s[j + 3];
            float p0 = p_s[j * H + hh],       p1 = p_s[(j + 1) * H + hh];
            float p2 = p_s[(j + 2) * H + hh], p3 = p_s[(j + 3) * H + hh];
            const TIN* r0 = h + (size_t)s0 * C + c0;
            const TIN* r1 = h + (size_t)s1 * C + c0;
            const TIN* r2 = h + (size_t)s2 * C + c0;
            const TIN* r3 = h + (size_t)s3 * C + c0;
            if constexpr (V == 4) {
                float4 a0 = ld4f(r0), a1 = ld4f(r1), a2 = ld4f(r2), a3 = ld4f(r3);
                acc[0] = fmaf(p0, a0.x, fmaf(p1, a1.x, fmaf(p2, a2.x, fmaf(p3, a3.x, acc[0]))));
                acc[1] = fmaf(p0, a0.y, fmaf(p1, a1.y, fmaf(p2, a2.y, fmaf(p3, a3.y, acc[1]))));
                acc[2] = fmaf(p0, a0.z, fmaf(p1, a1.z, fmaf(p2, a2.z, fmaf(p3, a3.z, acc[2]))));
                acc[3] = fmaf(p0, a0.w, fmaf(p1, a1.w, fmaf(p2, a2.w, fmaf(p3, a3.w, acc[3]))));
            } else if constexpr (V == 2) {
                float2 a0 = ld2f(r0), a1 = ld2f(r1), a2 = ld2f(r2), a3 = ld2f(r3);
                acc[0] = fmaf(p0, a0.x, fmaf(p1, a1.x, fmaf(p2, a2.x, fmaf(p3, a3.x, acc[0]))));
                acc[1] = fmaf(p0, a0.y, fmaf(p1, a1.y, fmaf(p2, a2.y, fmaf(p3, a3.y, acc[1]))));
            } else {
                acc[0] = fmaf(p0, ldf(r0), fmaf(p1, ldf(r1), fmaf(p2, ldf(r2), fmaf(p3, ldf(r3), acc[0]))));
            }
        }
        for (; j < len; ++j) {
            int s0 = col_s[j];
            float p0 = p_s[j * H + hh];
            const TIN* r0 = h + (size_t)s0 * C + c0;
            if constexpr (V == 4) {
                float4 a0 = ld4f(r0);
                acc[0] = fmaf(p0, a0.x, acc[0]);
                acc[1] = fmaf(p0, a0.y, acc[1]);
                acc[2] = fmaf(p0, a0.z, acc[2]);
                acc[3] = fmaf(p0, a0.w, acc[3]);
            } else if constexpr (V == 2) {
                float2 a0 = ld2f(r0);
                acc[0] = fmaf(p0, a0.x, acc[0]);
                acc[1] = fmaf(p0, a0.y, acc[1]);
            } else {
                acc[0] = fmaf(p0, ldf(r0), acc[0]);
            }
        }
    }

    float o[V];
    #pragma unroll
    for (int v = 0; v < V; ++v) {
        o[v] = acc[v] + bias[c0 + v];
        if (DO_ELU) o[v] = (o[v] > 0.f) ? o[v] : expm1f(o[v]);
    }
    if constexpr (sizeof(TOUT) == 2) {
        unsigned int* op = (unsigned int*)(out + (size_t)node * C + c0);
        if constexpr (V == 4) {
            u32x2 w;
            w.x = pack2bf(o[0], o[1]);
            w.y = pack2bf(o[2], o[3]);
            __builtin_nontemporal_store(w, (u32x2*)op);
        } else if constexpr (V == 2) {
            __builtin_nontemporal_store(pack2bf(o[0], o[1]), op);
        } else {
            *(unsigned short*)op = f2bf(o[0]);
        }
    } else {
        float* op = (float*)out + (size_t)node * C + c0;
        #pragma unroll
        for (int v = 0; v < V; ++v) __builtin_nontemporal_store(o[v], op + v);
    }
}

// ---------------------------------------------------------------------------

extern "C" void kernel_launch(void* const* d_in, const int* in_sizes, int n_in,
                              void* d_out, int out_size, void* d_ws, size_t ws_size,
                              hipStream_t stream) {
    const float* x   = (const float*)d_in[0];
    const int*   ei  = (const int*)d_in[1];
    const float* W1  = (const float*)d_in[2];
    const float* as1 = (const float*)d_in[3];
    const float* ad1 = (const float*)d_in[4];
    const float* b1  = (const float*)d_in[5];
    const float* W2  = (const float*)d_in[6];
    const float* as2 = (const float*)d_in[7];
    const float* ad2 = (const float*)d_in[8];
    const float* b2  = (const float*)d_in[9];
    const float* W3  = (const float*)d_in[10];
    const float* as3 = (const float*)d_in[11];
    const float* ad3 = (const float*)d_in[12];
    const float* b3  = (const float*)d_in[13];
    float*       out = (float*)d_out;

    const int N = in_sizes[0] / 256;     // 50000
    const int E = in_sizes[1] / 2;       // 400000

    typedef unsigned short bf;
    size_t off = 0;
    auto alloc = [&](size_t bytes) -> void* {
        void* p = (char*)d_ws + off;
        off += (bytes + 255) & ~(size_t)255;
        return p;
    };
    float* asb    = (float*)alloc((size_t)N * 8 * 4);
    float* adb    = (float*)alloc((size_t)N * 8 * 4);
    float* mArr   = (float*)alloc((size_t)N * 8 * 4);
    float* invArr = (float*)alloc((size_t)N * 8 * 4);
    int*   deg    = (int*)alloc((size_t)N * 4);
    int*   offs   = (int*)alloc((size_t)(N + 1) * 4);
    int*   cursor = (int*)alloc((size_t)N * 4);
    int*   col    = (int*)alloc((size_t)(E + N) * 4);
    bf*    W1t    = (bf*)alloc((size_t)256 * 1024 * 2);
    bf*    W2t    = (bf*)alloc((size_t)1024 * 512 * 2);
    const size_t NB = (size_t)N * 1024;
    bf* B1 = (bf*)alloc(NB * 2);
    bf* B2 = (bf*)alloc(NB * 2);
    bf* x_bf = B2;   // x_bf (25.6MB) lives in B2's region; dead before agg1 writes B2

    // ---- CSR build ----
    (void)hipMemsetAsync(deg, 0, (size_t)N * 4, stream);
    count_kernel<<<(E + 255) / 256, 256, 0, stream>>>(ei, deg, E, N);
    scan_kernel<<<1, 1024, 0, stream>>>(deg, offs, cursor, N);
    fill_kernel<<<(E + N + 255) / 256, 256, 0, stream>>>(ei, cursor, col, E, N);

    // ---- prep: x -> bf16, W1/W2 -> transposed bf16 ----
    {
        int n4 = N * 256 / 4;
        cvt_bf_kernel<<<(n4 + 255) / 256, 256, 0, stream>>>(x, x_bf, n4);
        transpose_bf_kernel<<<dim3(1024 / 16, 256 / 16), dim3(16, 16), 0, stream>>>(W1, W1t, 256, 1024);
        transpose_bf_kernel<<<dim3(512 / 16, 1024 / 16), dim3(16, 16), 0, stream>>>(W2, W2t, 1024, 512);
    }

    const int MBm = (N + 127) / 128;
    const int AB  = (N + 3) / 4;        // 4 nodes (waves) per block

    // ---- layer 1: 256 -> 8 x 128 (MFMA) ----
    gemm_mfma<256, 1024, bf><<<dim3(MBm, 8), 256, 0, stream>>>(x_bf, W1t, B1, N);
    alpha128_kernel<8><<<AB, 256, 0, stream>>>(B1, as1, ad1, asb, adb, N);
    norm_kernel<8><<<AB, 256, 0, stream>>>(asb, adb, offs, col, mArr, invArr, N);
    agg_kernel<8, 128, 256, true, bf, bf><<<N, 256, 0, stream>>>(B1, asb, adb, mArr, invArr, offs, col, b1, B2, N);

    // ---- layer 2: 1024 -> 4 x 128 (MFMA) ----
    gemm_mfma<1024, 512, bf><<<dim3(MBm, 4), 256, 0, stream>>>(B2, W2t, B1, N);
    alpha128_kernel<4><<<AB, 256, 0, stream>>>(B1, as2, ad2, asb, adb, N);
    norm_kernel<4><<<AB, 256, 0, stream>>>(asb, adb, offs, col, mArr, invArr, N);
    agg_kernel<4, 128, 256, true, bf, bf><<<N, 256, 0, stream>>>(B1, asb, adb, mArr, invArr, offs, col, b2, B2, N);

    // ---- layer 3: 512 -> 1 x 64 (fp32 vector, accuracy hedge) ----
    gemm_kernel<512, 64, bf, bf><<<dim3(MBm, 1), 256, 0, stream>>>(B2, W3, B1, N);
    alpha_kernel<1, 64, bf><<<(N + 3) / 4, 256, 0, stream>>>(B1, as3, ad3, asb, adb, N);
    norm_kernel<1><<<AB, 256, 0, stream>>>(asb, adb, offs, col, mArr, invArr, N);
    agg_kernel<1, 64, 64, false, bf, float><<<N, 64, 0, stream>>>(B1, asb, adb, mArr, invArr, offs, col, b3, out, N);
}